// Round 2
// baseline (2117.337 us; speedup 1.0000x reference)
//
#include <hip/hip_runtime.h>

// ---------- types / helpers ----------
typedef __attribute__((ext_vector_type(8))) short short8;
typedef __attribute__((ext_vector_type(4))) float f32x4;

#define DI __device__ __forceinline__

DI unsigned short f2bf(float x) {
  unsigned int u = __float_as_uint(x);
  u += 0x7fff + ((u >> 16) & 1);   // round-to-nearest-even
  return (unsigned short)(u >> 16);
}
DI float bf2f(unsigned short u) { return __uint_as_float(((unsigned int)u) << 16); }

DI void gload16(const void* g, void* l) {
  __builtin_amdgcn_global_load_lds(
      (const __attribute__((address_space(1))) unsigned int*)g,
      (__attribute__((address_space(3))) unsigned int*)l, 16, 0, 0);
}

DI float sigm(float x) { return 1.f / (1.f + __expf(-x)); }
DI float tanh_(float x) { return 2.f / (1.f + __expf(-2.f * x)) - 1.f; }

// ---------- f32 -> bf16 (single) ----------
__global__ __launch_bounds__(256) void cvt4(const float* __restrict__ in,
                                            unsigned short* __restrict__ out, int n4) {
  int i = blockIdx.x * 256 + threadIdx.x;
  if (i >= n4) return;
  float4 v = ((const float4*)in)[i];
  ushort4 o;
  o.x = f2bf(v.x); o.y = f2bf(v.y); o.z = f2bf(v.z); o.w = f2bf(v.w);
  ((ushort4*)out)[i] = o;
}

// ---------- f32 -> bf16 hi/lo split ----------
__global__ __launch_bounds__(256) void split4(const float* __restrict__ in,
                                              unsigned short* __restrict__ hi,
                                              unsigned short* __restrict__ lo, int n4) {
  int i = blockIdx.x * 256 + threadIdx.x;
  if (i >= n4) return;
  float4 v = ((const float4*)in)[i];
  ushort4 h, l;
  h.x = f2bf(v.x); l.x = f2bf(v.x - bf2f(h.x));
  h.y = f2bf(v.y); l.y = f2bf(v.y - bf2f(h.y));
  h.z = f2bf(v.z); l.z = f2bf(v.z - bf2f(h.z));
  h.w = f2bf(v.w); l.w = f2bf(v.w - bf2f(h.w));
  ((ushort4*)hi)[i] = h;
  ((ushort4*)lo)[i] = l;
}

// ---------- split-precision bf16 GEMM: C[M,N] = A[M,K]*B[N,K]^T (fp32-accurate) ----------
// C = Ahi*Bhi^T + Alo*Bhi^T + Ahi*Blo^T; OUTMODE 1 adds bias1[col]+bias2[col]
template <int OUTMODE>
__global__ __launch_bounds__(256, 2)
void gemm3_bt(const unsigned short* __restrict__ Ahi, const unsigned short* __restrict__ Alo,
              const unsigned short* __restrict__ Bhi, const unsigned short* __restrict__ Blo,
              float* __restrict__ C, const float* __restrict__ bias1,
              const float* __restrict__ bias2, int M, int N, int K) {
  __shared__ alignas(16) unsigned short Ah[128 * 32];
  __shared__ alignas(16) unsigned short Al[128 * 32];
  __shared__ alignas(16) unsigned short Bh[128 * 32];
  __shared__ alignas(16) unsigned short Bl[128 * 32];
  const int t = threadIdx.x;
  const int lane = t & 63, wid = t >> 6;
  const int m0 = blockIdx.y * 128, n0 = blockIdx.x * 128;
  const int wm = (wid >> 1) * 64, wn = (wid & 1) * 64;
  const int lr = lane & 15, lk = (lane >> 4) * 8, lg = lane >> 4;

  f32x4 acc[4][4] = {};

  const int e0 = t, e1 = t + 256;
  const int ra0 = e0 >> 2, ka0 = (e0 & 3) << 3;
  const int ra1 = e1 >> 2, ka1 = (e1 & 3) << 3;

  for (int kt = 0; kt < K; kt += 32) {
    const size_t a0 = (size_t)(m0 + ra0) * K + kt + ka0;
    const size_t a1 = (size_t)(m0 + ra1) * K + kt + ka1;
    const size_t b0 = (size_t)(n0 + ra0) * K + kt + ka0;
    const size_t b1 = (size_t)(n0 + ra1) * K + kt + ka1;
    gload16(Ahi + a0, &Ah[e0 * 8]);
    gload16(Ahi + a1, &Ah[e1 * 8]);
    gload16(Alo + a0, &Al[e0 * 8]);
    gload16(Alo + a1, &Al[e1 * 8]);
    gload16(Bhi + b0, &Bh[e0 * 8]);
    gload16(Bhi + b1, &Bh[e1 * 8]);
    gload16(Blo + b0, &Bl[e0 * 8]);
    gload16(Blo + b1, &Bl[e1 * 8]);
    __syncthreads();
    short8 ah[4], al[4], bh[4], bl[4];
#pragma unroll
    for (int f = 0; f < 4; ++f) {
      ah[f] = *(const short8*)&Ah[(wm + f * 16 + lr) * 32 + lk];
      al[f] = *(const short8*)&Al[(wm + f * 16 + lr) * 32 + lk];
      bh[f] = *(const short8*)&Bh[(wn + f * 16 + lr) * 32 + lk];
      bl[f] = *(const short8*)&Bl[(wn + f * 16 + lr) * 32 + lk];
    }
#pragma unroll
    for (int i = 0; i < 4; ++i)
#pragma unroll
      for (int j = 0; j < 4; ++j) {
        acc[i][j] = __builtin_amdgcn_mfma_f32_16x16x32_bf16(ah[i], bh[j], acc[i][j], 0, 0, 0);
        acc[i][j] = __builtin_amdgcn_mfma_f32_16x16x32_bf16(al[i], bh[j], acc[i][j], 0, 0, 0);
        acc[i][j] = __builtin_amdgcn_mfma_f32_16x16x32_bf16(ah[i], bl[j], acc[i][j], 0, 0, 0);
      }
    __syncthreads();
  }

#pragma unroll
  for (int i = 0; i < 4; ++i) {
#pragma unroll
    for (int j = 0; j < 4; ++j) {
#pragma unroll
      for (int q = 0; q < 4; ++q) {
        int row = m0 + wm + i * 16 + lg * 4 + q;
        int col = n0 + wn + j * 16 + lr;
        float v = acc[i][j][q];
        if constexpr (OUTMODE == 1) v += bias1[col] + bias2[col];
        C[(size_t)row * N + col] = v;
      }
    }
  }
}

// ---------- mix1: n1t[(nt,w),c] = relu(sum_{k,v} node1[(nt,v),k*2048+c]*(db+dc)[k,v,w]) ----------
// fp32 in, hi/lo bf16 out
__global__ __launch_bounds__(256) void mix1(const float* __restrict__ node1,
                                            const float* __restrict__ dist,
                                            unsigned short* __restrict__ n1thi,
                                            unsigned short* __restrict__ n1tlo) {
  __shared__ float ds[288];
  const int nt = blockIdx.x, tid = threadIdx.x;
  for (int i = tid; i < 288; i += 256)
    ds[i] = dist[(size_t)nt * 576 + 288 + i] + dist[(size_t)nt * 576 + i];
  __syncthreads();
  const int c = blockIdx.y * 256 + tid;  // 0..2047
  float s[12];
#pragma unroll
  for (int w = 0; w < 12; ++w) s[w] = 0.f;
#pragma unroll
  for (int k = 0; k < 2; ++k)
#pragma unroll
    for (int v = 0; v < 12; ++v) {
      float x = node1[(size_t)(nt * 12 + v) * 4096 + k * 2048 + c];
      const float* d = &ds[k * 144 + v * 12];
#pragma unroll
      for (int w = 0; w < 12; ++w) s[w] = fmaf(x, d[w], s[w]);
    }
#pragma unroll
  for (int w = 0; w < 12; ++w) {
    float r = fmaxf(s[w], 0.f);
    unsigned short h = f2bf(r);
    n1thi[(size_t)(nt * 12 + w) * 2048 + c] = h;
    n1tlo[(size_t)(nt * 12 + w) * 2048 + c] = f2bf(r - bf2f(h));
  }
}

// ---------- mix2 + pooling: pooled[nt][0:3072] hi/lo bf16 ----------
__global__ __launch_bounds__(256) void mix2(const float* __restrict__ node2,
                                            const float* __restrict__ dist,
                                            unsigned short* __restrict__ phi,
                                            unsigned short* __restrict__ plo) {
  __shared__ float db[288], dc[288];
  const int nt = blockIdx.x, tid = threadIdx.x;
  for (int i = tid; i < 288; i += 256) {
    db[i] = dist[(size_t)nt * 576 + 288 + i];
    dc[i] = dist[(size_t)nt * 576 + i];
  }
  __syncthreads();
  const int c = blockIdx.y * 256 + tid;  // 0..1023
  float sb[12], sc[12];
#pragma unroll
  for (int w = 0; w < 12; ++w) { sb[w] = 0.f; sc[w] = 0.f; }
#pragma unroll
  for (int k = 0; k < 2; ++k)
#pragma unroll
    for (int v = 0; v < 12; ++v) {
      float x = node2[(size_t)(nt * 12 + v) * 2048 + k * 1024 + c];
      const float* pb = &db[k * 144 + v * 12];
      const float* pc = &dc[k * 144 + v * 12];
#pragma unroll
      for (int w = 0; w < 12; ++w) { sb[w] = fmaf(x, pb[w], sb[w]); sc[w] = fmaf(x, pc[w], sc[w]); }
    }
  float left = 0.f, right = 0.f, allf = 0.f;
#pragma unroll
  for (int w = 0; w < 6; ++w) left += fmaxf(sb[w], 0.f);
#pragma unroll
  for (int w = 6; w < 12; ++w) right += fmaxf(sb[w], 0.f);
#pragma unroll
  for (int w = 0; w < 12; ++w) allf += fmaxf(sc[w], 0.f);
  float vals[3] = {left * (1.f / 6.f), right * (1.f / 6.f), allf * (1.f / 12.f)};
#pragma unroll
  for (int p = 0; p < 3; ++p) {
    unsigned short h = f2bf(vals[p]);
    phi[(size_t)nt * 3072 + p * 1024 + c] = h;
    plo[(size_t)nt * 3072 + p * 1024 + c] = f2bf(vals[p] - bf2f(h));
  }
}

// ---------- LSTM recurrent GEMM: gates[20,8192] = xg[s] + h @ w_hh^T (plain bf16) ----------
__global__ __launch_bounds__(64) void lstm_hgemm(const unsigned short* __restrict__ h,
                                                 const unsigned short* __restrict__ W,
                                                 const float* __restrict__ xg,
                                                 float* __restrict__ gates, int s) {
  const int lane = threadIdx.x;
  const int col0 = blockIdx.x * 16;
  const int lr = lane & 15, lk = (lane >> 4) * 8, lg = lane >> 4;
  f32x4 acc0 = {}, acc1 = {};
  const unsigned short* wp = W + (size_t)(col0 + lr) * 2048 + lk;
  const unsigned short* h0p = h + (size_t)lr * 2048 + lk;
  const unsigned short* h1p = h + (size_t)(16 + lr) * 2048 + lk;
  const bool v1 = (16 + lr) < 20;
#pragma unroll 4
  for (int kt = 0; kt < 2048; kt += 32) {
    short8 b = *(const short8*)(wp + kt);
    short8 a0 = *(const short8*)(h0p + kt);
    short8 a1 = {0, 0, 0, 0, 0, 0, 0, 0};
    if (v1) a1 = *(const short8*)(h1p + kt);
    acc0 = __builtin_amdgcn_mfma_f32_16x16x32_bf16(a0, b, acc0, 0, 0, 0);
    acc1 = __builtin_amdgcn_mfma_f32_16x16x32_bf16(a1, b, acc1, 0, 0, 0);
  }
  const int col = col0 + lr;
#pragma unroll
  for (int q = 0; q < 4; ++q) {
    int r0 = lg * 4 + q;
    gates[(size_t)r0 * 8192 + col] = acc0[q] + xg[(size_t)(s * 20 + r0) * 8192 + col];
    int r1 = 16 + lg * 4 + q;
    if (r1 < 20)
      gates[(size_t)r1 * 8192 + col] = acc1[q] + xg[(size_t)(s * 20 + r1) * 8192 + col];
  }
}

// ---------- LSTM pointwise ----------
__global__ __launch_bounds__(256) void lstm_point(const float* __restrict__ g,
                                                  float* __restrict__ cst,
                                                  unsigned short* __restrict__ hbf,
                                                  float* __restrict__ vf, int s) {
  int idx = blockIdx.x * 256 + threadIdx.x;  // < 40960
  int t = idx >> 11, c = idx & 2047;
  float gi = g[(size_t)t * 8192 + c];
  float gf = g[(size_t)t * 8192 + 2048 + c];
  float gg = g[(size_t)t * 8192 + 4096 + c];
  float go = g[(size_t)t * 8192 + 6144 + c];
  float cp = (s == 0) ? 0.f : cst[idx];
  float cn = sigm(gf) * cp + sigm(gi) * tanh_(gg);
  float hv = sigm(go) * tanh_(cn);
  cst[idx] = cn;
  hbf[idx] = f2bf(hv);
  vf[(size_t)(s * 20 + t) * 2048 + c] = hv;
}

// ---------- group_cls ----------
__global__ __launch_bounds__(256) void gcls(const float* __restrict__ vf,
                                            const float* __restrict__ Wc,
                                            const float* __restrict__ bc,
                                            float* __restrict__ out) {
  const int n = blockIdx.x;
  const int j = threadIdx.x >> 5, l = threadIdx.x & 31;
  const float* v = vf + (size_t)(n * 20 + 19) * 2048;
  const float* w = Wc + (size_t)j * 2048;
  float s = 0.f;
  for (int c = l; c < 2048; c += 32) s += v[c] * w[c];
  for (int off = 16; off > 0; off >>= 1) s += __shfl_down(s, off, 32);
  if (l == 0) out[n * 8 + j] = s + bc[j];
}

// ---------- host ----------
extern "C" void kernel_launch(void* const* d_in, const int* in_sizes, int n_in,
                              void* d_out, int out_size, void* d_ws, size_t ws_size,
                              hipStream_t stream) {
  const float* base_out = (const float*)d_in[0];
  const float* dist = (const float*)d_in[1];
  const float* W1 = (const float*)d_in[2];
  const float* W2 = (const float*)d_in[3];
  const float* w_ih = (const float*)d_in[4];
  const float* w_hh = (const float*)d_in[5];
  const float* b_ih = (const float*)d_in[6];
  const float* b_hh = (const float*)d_in[7];
  const float* Wc = (const float*)d_in[8];
  const float* bc = (const float*)d_in[9];
  float* out = (float*)d_out;

  char* ws = (char*)d_ws;
  // Region A [0, 125829120): A1hi/A1lo during GEMM1; then n1t/W2/pooled/whh
  unsigned short* A1hi = (unsigned short*)(ws + 0);                  // 60MB
  unsigned short* A1lo = (unsigned short*)(ws + 62914560);           // 60MB
  unsigned short* n1thi = (unsigned short*)(ws + 0);                 // 30MB
  unsigned short* n1tlo = (unsigned short*)(ws + 31457280);          // 30MB
  unsigned short* W2hi = (unsigned short*)(ws + 62914560);           // 8MB
  unsigned short* W2lo = (unsigned short*)(ws + 71303168);           // 8MB
  unsigned short* phi = (unsigned short*)(ws + 79691776);            // 3.75MB
  unsigned short* plo = (unsigned short*)(ws + 83623936);            // 3.75MB
  unsigned short* whhbf = (unsigned short*)(ws + 87556096);          // 32MB (ends 121110528)
  // Region B [125829120, 226492416): W1hi/W1lo during GEMM1; then wih hi/lo
  unsigned short* W1hi = (unsigned short*)(ws + 125829120);          // 32MB
  unsigned short* W1lo = (unsigned short*)(ws + 159383552);          // 32MB
  unsigned short* wihhi = (unsigned short*)(ws + 125829120);         // 48MB
  unsigned short* wihlo = (unsigned short*)(ws + 176160768);         // 48MB (ends 226492416)
  // Region C [226492416, 352321536): node1 f32; then node2 f32 + xg + LSTM scratch
  float* node1 = (float*)(ws + 226492416);                           // 120MB
  float* node2 = (float*)(ws + 226492416);                           // 60MB
  float* xg = (float*)(ws + 289406976);                              // 20MB (ends 310378496)
  float* gates = (float*)(ws + 310378496);                           // 640KB
  float* cst = (float*)(ws + 311033856);                             // 160KB
  unsigned short* hbf = (unsigned short*)(ws + 311197696);           // 80KB

  // 1) split inputs needed for GEMM1
  split4<<<30720, 256, 0, stream>>>(base_out, A1hi, A1lo, 7864320);
  split4<<<16384, 256, 0, stream>>>(W1, W1hi, W1lo, 4194304);

  // 2) GEMM1: node1[(nt,v), o] = base_out·W1^T  [7680,4096]x[4096,4096] fp32-accurate
  gemm3_bt<0><<<dim3(32, 60), 256, 0, stream>>>(A1hi, A1lo, W1hi, W1lo, node1,
                                                nullptr, nullptr, 7680, 4096, 4096);

  // 3) remaining weight conversions (reuse regions A/B — safe after GEMM1 in stream order)
  split4<<<4096, 256, 0, stream>>>(W2, W2hi, W2lo, 1048576);
  split4<<<24576, 256, 0, stream>>>(w_ih, wihhi, wihlo, 6291456);
  cvt4<<<16384, 256, 0, stream>>>(w_hh, whhbf, 4194304);

  // 4) mix1 -> n1t hi/lo
  mix1<<<dim3(640, 8), 256, 0, stream>>>(node1, dist, n1thi, n1tlo);

  // 5) GEMM2: node2 = n1t·W2^T  [7680,2048]x[2048,2048]
  gemm3_bt<0><<<dim3(16, 60), 256, 0, stream>>>(n1thi, n1tlo, W2hi, W2lo, node2,
                                                nullptr, nullptr, 7680, 2048, 2048);

  // 6) mix2 + pooling -> pooled hi/lo
  mix2<<<dim3(640, 4), 256, 0, stream>>>(node2, dist, phi, plo);

  // 7) xg = pooled·w_ih^T + b_ih + b_hh  [640,3072]x[8192,3072]
  gemm3_bt<1><<<dim3(64, 5), 256, 0, stream>>>(phi, plo, wihhi, wihlo, xg,
                                               b_ih, b_hh, 640, 8192, 3072);

  // 8) LSTM: 32 steps, batch 20
  lstm_point<<<160, 256, 0, stream>>>(xg, cst, hbf, out + 256, 0);
  for (int s = 1; s < 32; ++s) {
    lstm_hgemm<<<512, 64, 0, stream>>>(hbf, whhbf, xg, gates, s);
    lstm_point<<<160, 256, 0, stream>>>(gates, cst, hbf, out + 256, s);
  }
  // 9) group_cls
  gcls<<<32, 256, 0, stream>>>(out + 256, Wc, bc, out);
}

// Round 3
// 1353.735 us; speedup vs baseline: 1.5641x; 1.5641x over previous
//
#include <hip/hip_runtime.h>

// ---------- types / helpers ----------
typedef _Float16 f16x8 __attribute__((ext_vector_type(8)));
typedef _Float16 f16x4 __attribute__((ext_vector_type(4)));
typedef __attribute__((ext_vector_type(4))) float f32x4;

#define DI __device__ __forceinline__

DI void gload16(const void* g, void* l) {
  __builtin_amdgcn_global_load_lds(
      (const __attribute__((address_space(1))) unsigned int*)g,
      (__attribute__((address_space(3))) unsigned int*)l, 16, 0, 0);
}

DI float sigm(float x) { return 1.f / (1.f + __expf(-x)); }
DI float tanh_(float x) { return 2.f / (1.f + __expf(-2.f * x)) - 1.f; }

// ---------- f32 -> f16 conversion (x4) ----------
__global__ __launch_bounds__(256) void cvt4h(const float* __restrict__ in,
                                             _Float16* __restrict__ out, int n4) {
  int i = blockIdx.x * 256 + threadIdx.x;
  if (i >= n4) return;
  float4 v = ((const float4*)in)[i];
  f16x4 o;
  o[0] = (_Float16)v.x; o[1] = (_Float16)v.y; o[2] = (_Float16)v.z; o[3] = (_Float16)v.w;
  ((f16x4*)out)[i] = o;
}

// ---------- f16 GEMM: C[M,N] = A[M,K] * B[N,K]^T  (m97 structure) ----------
// OUTMODE 0: f16 out; 1: f32 out + bias1[col]+bias2[col]
template <int OUTMODE>
__global__ __launch_bounds__(256, 2)
void gemm_bt(const _Float16* __restrict__ A, const _Float16* __restrict__ B,
             void* __restrict__ Cout, const float* __restrict__ bias1,
             const float* __restrict__ bias2, int M, int N, int K) {
  __shared__ alignas(16) _Float16 Asm[128 * 32];
  __shared__ alignas(16) _Float16 Bsm[128 * 32];
  const int t = threadIdx.x;
  const int lane = t & 63, wid = t >> 6;
  const int m0 = blockIdx.y * 128, n0 = blockIdx.x * 128;
  const int wm = (wid >> 1) * 64, wn = (wid & 1) * 64;
  const int lr = lane & 15, lk = (lane >> 4) * 8, lg = lane >> 4;

  f32x4 acc[4][4] = {};

  const int e0 = t, e1 = t + 256;
  const int ra0 = e0 >> 2, ka0 = (e0 & 3) << 3;
  const int ra1 = e1 >> 2, ka1 = (e1 & 3) << 3;

  for (int kt = 0; kt < K; kt += 32) {
    gload16(A + (size_t)(m0 + ra0) * K + kt + ka0, &Asm[e0 * 8]);
    gload16(A + (size_t)(m0 + ra1) * K + kt + ka1, &Asm[e1 * 8]);
    gload16(B + (size_t)(n0 + ra0) * K + kt + ka0, &Bsm[e0 * 8]);
    gload16(B + (size_t)(n0 + ra1) * K + kt + ka1, &Bsm[e1 * 8]);
    __syncthreads();
    f16x8 af[4], bfr[4];
#pragma unroll
    for (int f = 0; f < 4; ++f) {
      af[f] = *(const f16x8*)&Asm[(wm + f * 16 + lr) * 32 + lk];
      bfr[f] = *(const f16x8*)&Bsm[(wn + f * 16 + lr) * 32 + lk];
    }
#pragma unroll
    for (int i = 0; i < 4; ++i)
#pragma unroll
      for (int j = 0; j < 4; ++j)
        acc[i][j] = __builtin_amdgcn_mfma_f32_16x16x32_f16(af[i], bfr[j], acc[i][j], 0, 0, 0);
    __syncthreads();
  }

#pragma unroll
  for (int i = 0; i < 4; ++i) {
#pragma unroll
    for (int j = 0; j < 4; ++j) {
#pragma unroll
      for (int q = 0; q < 4; ++q) {
        int row = m0 + wm + i * 16 + lg * 4 + q;
        int col = n0 + wn + j * 16 + lr;
        if constexpr (OUTMODE == 0) {
          ((_Float16*)Cout)[(size_t)row * N + col] = (_Float16)acc[i][j][q];
        } else {
          ((float*)Cout)[(size_t)row * N + col] = acc[i][j][q] + bias1[col] + bias2[col];
        }
      }
    }
  }
}

// ---------- mix1: n1t[(nt,w),c] = relu(sum_{k,v} node1[(nt,v),k*2048+c]*(db+dc)[k,v,w]) ----------
__global__ __launch_bounds__(256) void mix1(const _Float16* __restrict__ node1,
                                            const float* __restrict__ dist,
                                            _Float16* __restrict__ n1t) {
  __shared__ float ds[288];
  const int nt = blockIdx.x, tid = threadIdx.x;
  for (int i = tid; i < 288; i += 256)
    ds[i] = dist[(size_t)nt * 576 + 288 + i] + dist[(size_t)nt * 576 + i];
  __syncthreads();
  const int c = blockIdx.y * 256 + tid;  // 0..2047
  float s[12];
#pragma unroll
  for (int w = 0; w < 12; ++w) s[w] = 0.f;
#pragma unroll
  for (int k = 0; k < 2; ++k)
#pragma unroll
    for (int v = 0; v < 12; ++v) {
      float x = (float)node1[(size_t)(nt * 12 + v) * 4096 + k * 2048 + c];
      const float* d = &ds[k * 144 + v * 12];
#pragma unroll
      for (int w = 0; w < 12; ++w) s[w] = fmaf(x, d[w], s[w]);
    }
#pragma unroll
  for (int w = 0; w < 12; ++w)
    n1t[(size_t)(nt * 12 + w) * 2048 + c] = (_Float16)fmaxf(s[w], 0.f);
}

// ---------- mix2 + pooling: pooled[nt][0:3072] f16 ----------
__global__ __launch_bounds__(256) void mix2(const _Float16* __restrict__ node2,
                                            const float* __restrict__ dist,
                                            _Float16* __restrict__ pooled) {
  __shared__ float db[288], dc[288];
  const int nt = blockIdx.x, tid = threadIdx.x;
  for (int i = tid; i < 288; i += 256) {
    db[i] = dist[(size_t)nt * 576 + 288 + i];
    dc[i] = dist[(size_t)nt * 576 + i];
  }
  __syncthreads();
  const int c = blockIdx.y * 256 + tid;  // 0..1023
  float sb[12], sc[12];
#pragma unroll
  for (int w = 0; w < 12; ++w) { sb[w] = 0.f; sc[w] = 0.f; }
#pragma unroll
  for (int k = 0; k < 2; ++k)
#pragma unroll
    for (int v = 0; v < 12; ++v) {
      float x = (float)node2[(size_t)(nt * 12 + v) * 2048 + k * 1024 + c];
      const float* pb = &db[k * 144 + v * 12];
      const float* pc = &dc[k * 144 + v * 12];
#pragma unroll
      for (int w = 0; w < 12; ++w) { sb[w] = fmaf(x, pb[w], sb[w]); sc[w] = fmaf(x, pc[w], sc[w]); }
    }
  float left = 0.f, right = 0.f, allf = 0.f;
#pragma unroll
  for (int w = 0; w < 6; ++w) left += fmaxf(sb[w], 0.f);
#pragma unroll
  for (int w = 6; w < 12; ++w) right += fmaxf(sb[w], 0.f);
#pragma unroll
  for (int w = 0; w < 12; ++w) allf += fmaxf(sc[w], 0.f);
  pooled[(size_t)nt * 3072 + c] = (_Float16)(left * (1.f / 6.f));
  pooled[(size_t)nt * 3072 + 1024 + c] = (_Float16)(right * (1.f / 6.f));
  pooled[(size_t)nt * 3072 + 2048 + c] = (_Float16)(allf * (1.f / 12.f));
}

// ---------- LSTM recurrent GEMM: gates[20,8192] = xg[s] + h @ w_hh^T ----------
__global__ __launch_bounds__(64) void lstm_hgemm(const _Float16* __restrict__ h,
                                                 const _Float16* __restrict__ W,
                                                 const float* __restrict__ xg,
                                                 float* __restrict__ gates, int s) {
  const int lane = threadIdx.x;
  const int col0 = blockIdx.x * 16;
  const int lr = lane & 15, lk = (lane >> 4) * 8, lg = lane >> 4;
  f32x4 acc0 = {}, acc1 = {};
  const _Float16* wp = W + (size_t)(col0 + lr) * 2048 + lk;
  const _Float16* h0p = h + (size_t)lr * 2048 + lk;
  const _Float16* h1p = h + (size_t)(16 + lr) * 2048 + lk;
  const bool v1 = (16 + lr) < 20;
#pragma unroll 4
  for (int kt = 0; kt < 2048; kt += 32) {
    f16x8 b = *(const f16x8*)(wp + kt);
    f16x8 a0 = *(const f16x8*)(h0p + kt);
    f16x8 a1 = {0, 0, 0, 0, 0, 0, 0, 0};
    if (v1) a1 = *(const f16x8*)(h1p + kt);
    acc0 = __builtin_amdgcn_mfma_f32_16x16x32_f16(a0, b, acc0, 0, 0, 0);
    acc1 = __builtin_amdgcn_mfma_f32_16x16x32_f16(a1, b, acc1, 0, 0, 0);
  }
  const int col = col0 + lr;
#pragma unroll
  for (int q = 0; q < 4; ++q) {
    int r0 = lg * 4 + q;
    gates[(size_t)r0 * 8192 + col] = acc0[q] + xg[(size_t)(s * 20 + r0) * 8192 + col];
    int r1 = 16 + lg * 4 + q;
    if (r1 < 20)
      gates[(size_t)r1 * 8192 + col] = acc1[q] + xg[(size_t)(s * 20 + r1) * 8192 + col];
  }
}

// ---------- LSTM pointwise ----------
__global__ __launch_bounds__(256) void lstm_point(const float* __restrict__ g,
                                                  float* __restrict__ cst,
                                                  _Float16* __restrict__ hh,
                                                  float* __restrict__ vf, int s) {
  int idx = blockIdx.x * 256 + threadIdx.x;  // < 40960
  int t = idx >> 11, c = idx & 2047;
  float gi = g[(size_t)t * 8192 + c];
  float gf = g[(size_t)t * 8192 + 2048 + c];
  float gg = g[(size_t)t * 8192 + 4096 + c];
  float go = g[(size_t)t * 8192 + 6144 + c];
  float cp = (s == 0) ? 0.f : cst[idx];
  float cn = sigm(gf) * cp + sigm(gi) * tanh_(gg);
  float hv = sigm(go) * tanh_(cn);
  cst[idx] = cn;
  hh[idx] = (_Float16)hv;
  vf[(size_t)(s * 20 + t) * 2048 + c] = hv;
}

// ---------- group_cls ----------
__global__ __launch_bounds__(256) void gcls(const float* __restrict__ vf,
                                            const float* __restrict__ Wc,
                                            const float* __restrict__ bc,
                                            float* __restrict__ out) {
  const int n = blockIdx.x;
  const int j = threadIdx.x >> 5, l = threadIdx.x & 31;
  const float* v = vf + (size_t)(n * 20 + 19) * 2048;
  const float* w = Wc + (size_t)j * 2048;
  float s = 0.f;
  for (int c = l; c < 2048; c += 32) s += v[c] * w[c];
  for (int off = 16; off > 0; off >>= 1) s += __shfl_down(s, off, 32);
  if (l == 0) out[n * 8 + j] = s + bc[j];
}

// ---------- host ----------
extern "C" void kernel_launch(void* const* d_in, const int* in_sizes, int n_in,
                              void* d_out, int out_size, void* d_ws, size_t ws_size,
                              hipStream_t stream) {
  const float* base_out = (const float*)d_in[0];
  const float* dist = (const float*)d_in[1];
  const float* W1 = (const float*)d_in[2];
  const float* W2 = (const float*)d_in[3];
  const float* w_ih = (const float*)d_in[4];
  const float* w_hh = (const float*)d_in[5];
  const float* b_ih = (const float*)d_in[6];
  const float* b_hh = (const float*)d_in[7];
  const float* Wc = (const float*)d_in[8];
  const float* bc = (const float*)d_in[9];
  float* out = (float*)d_out;

  char* ws = (char*)d_ws;
  const size_t MB = 1048576;
  _Float16* Ahf   = (_Float16*)(ws + 0);            // 60MB  [0,60)   dead after GEMM1
  _Float16* W1hf  = (_Float16*)(ws + 60 * MB);      // 32MB  [60,92)  dead after GEMM1
  _Float16* node1 = (_Float16*)(ws + 92 * MB);      // 60MB  [92,152)
  _Float16* whhhf = (_Float16*)(ws + 152 * MB);     // 32MB  [152,184)
  _Float16* wihhf = (_Float16*)(ws + 184 * MB);     // 48MB  [184,232)
  float* xg       = (float*)(ws + 232 * MB);        // 20MB  [232,252)
  float* gates    = (float*)(ws + 252 * MB);        // 640KB
  float* cst      = (float*)(ws + 253 * MB);        // 160KB
  _Float16* hbuf  = (_Float16*)(ws + 254 * MB);     // 80KB
  _Float16* W2hf  = (_Float16*)(ws + 255 * MB);     // 8MB   [255,263)
  _Float16* pooled= (_Float16*)(ws + 263 * MB);     // 3.75MB[263,267)
  // reuse of Ahf region after GEMM1:
  _Float16* n1t   = (_Float16*)(ws + 0);            // 30MB  [0,30)
  _Float16* node2 = (_Float16*)(ws + 30 * MB);      // 30MB  [30,60)

  // 1) conversions
  cvt4h<<<30720, 256, 0, stream>>>(base_out, Ahf, 7864320);
  cvt4h<<<16384, 256, 0, stream>>>(W1, W1hf, 4194304);
  cvt4h<<<4096, 256, 0, stream>>>(W2, W2hf, 1048576);
  cvt4h<<<24576, 256, 0, stream>>>(w_ih, wihhf, 6291456);
  cvt4h<<<16384, 256, 0, stream>>>(w_hh, whhhf, 4194304);

  // 2) GEMM1: node1[(nt,v), o] = base_out·W1^T  [7680,4096]x[4096,4096]
  gemm_bt<0><<<dim3(32, 60), 256, 0, stream>>>(Ahf, W1hf, node1, nullptr, nullptr,
                                               7680, 4096, 4096);
  // 3) mix1 -> n1t[(nt,w), c]
  mix1<<<dim3(640, 8), 256, 0, stream>>>(node1, dist, n1t);
  // 4) GEMM2: node2 = n1t·W2^T  [7680,2048]x[2048,2048]
  gemm_bt<0><<<dim3(16, 60), 256, 0, stream>>>(n1t, W2hf, node2, nullptr, nullptr,
                                               7680, 2048, 2048);
  // 5) mix2 + pooling -> pooled
  mix2<<<dim3(640, 4), 256, 0, stream>>>(node2, dist, pooled);
  // 6) xg = pooled·w_ih^T + b_ih + b_hh  [640,3072]x[8192,3072]
  gemm_bt<1><<<dim3(64, 5), 256, 0, stream>>>(pooled, wihhf, xg, b_ih, b_hh,
                                              640, 8192, 3072);
  // 7) LSTM: 32 steps, batch 20
  lstm_point<<<160, 256, 0, stream>>>(xg, cst, hbuf, out + 256, 0);
  for (int s = 1; s < 32; ++s) {
    lstm_hgemm<<<512, 64, 0, stream>>>(hbuf, whhhf, xg, gates, s);
    lstm_point<<<160, 256, 0, stream>>>(gates, cst, hbuf, out + 256, s);
  }
  // 8) group_cls
  gcls<<<32, 256, 0, stream>>>(out + 256, Wc, bc, out);
}